// Round 1
// 9951.402 us; speedup vs baseline: 1.2962x; 1.2962x over previous
//
#include <hip/hip_runtime.h>
#include <hip/hip_bf16.h>
#include <math.h>

// Problem constants
#define Bb 4
#define Tt 512
#define Cc 768
#define Hh 12
#define Ll 8
#define Vv 512
#define FFf 3072
#define HDd 64

typedef __hip_bfloat16 bf16;

__device__ __forceinline__ float b2f(bf16 x){ return __bfloat162float(x); }
__device__ __forceinline__ bf16 f2b(float x){ return __float2bfloat16(x); }

// dtype-flexible input load / output store. f32!=0 -> buffers are float32,
// else bf16. Flag is wave-uniform (read from ws) -> no divergence cost.
__device__ __forceinline__ float ldin(const void* p, size_t i, int f32){
  return f32 ? ((const float*)p)[i] : b2f(((const bf16*)p)[i]);
}
__device__ __forceinline__ void stout(void* p, size_t i, float v, int f32){
  if(f32) ((float*)p)[i] = v; else ((bf16*)p)[i] = f2b(v);
}

// ---------------- dtype detect: scan tok_emb viewed as bf16 ----------------
// f32-stored data viewed as u16: mantissa halfwords have random exponent
// fields -> some |v| >= 2^17 guaranteed. Real bf16 data here is ~N(0,0.02).
__global__ __launch_bounds__(256) void detect_kernel(const void* tok, int* flag){
  __shared__ int any;
  int tid = threadIdx.x;
  if(tid==0) any = 0;
  __syncthreads();
  const unsigned short* u = (const unsigned short*)tok;
  int local = 0;
  for(int i = tid; i < 16384; i += 256){     // 32 KB: safe for both widths
    unsigned short e = (u[i] >> 7) & 0xFF;   // exponent field of bf16 view
    if(e >= 0x90) local = 1;                 // |v| >= 2^17
  }
  if(local) any = 1;
  __syncthreads();
  if(tid==0) flag[0] = any;                  // 1 => float32 I/O
}

// ---------------- embeddings: x = tok[idx] + pos + type[1] ----------------
__global__ __launch_bounds__(256) void embed_kernel(const int* __restrict__ idx,
    const void* __restrict__ tok, const void* __restrict__ typ,
    const void* __restrict__ pos, float* __restrict__ x, const int* flagp){
  int f32 = *flagp;
  int i = blockIdx.x*256 + threadIdx.x;       // over B*T*C
  int c = i % Cc;
  int bt = i / Cc;
  int t = bt % Tt;
  int row = idx[bt];
  x[i] = ldin(tok,(size_t)row*Cc+c,f32) + ldin(pos,(size_t)t*Cc+c,f32)
       + ldin(typ,(size_t)Cc+c,f32);
}

// ---------------- LayerNorm over C=768, one block per row ----------------
// w/b read at element offset po. Optionally mirrors result to out (bf16/f32).
__global__ __launch_bounds__(256) void ln_kernel(const float* __restrict__ x,
    const void* __restrict__ w, const void* __restrict__ b, size_t po,
    float* __restrict__ out, void* __restrict__ outBase, size_t off0,
    const int* flagp){
  int f32 = *flagp;
  int row = blockIdx.x, tid = threadIdx.x;
  const float* xr = x + (size_t)row*Cc;
  float v0=xr[tid], v1=xr[tid+256], v2=xr[tid+512];
  __shared__ float red[256];
  red[tid]=v0+v1+v2; __syncthreads();
  for(int off=128; off>0; off>>=1){ if(tid<off) red[tid]+=red[tid+off]; __syncthreads(); }
  float mean = red[0]*(1.0f/Cc);
  __syncthreads();
  float d0=v0-mean, d1=v1-mean, d2=v2-mean;
  red[tid]=d0*d0+d1*d1+d2*d2; __syncthreads();
  for(int off=128; off>0; off>>=1){ if(tid<off) red[tid]+=red[tid+off]; __syncthreads(); }
  float rstd = rsqrtf(red[0]*(1.0f/Cc) + 1e-5f);
  float o0 = d0*rstd*ldin(w,po+tid    ,f32) + ldin(b,po+tid    ,f32);
  float o1 = d1*rstd*ldin(w,po+tid+256,f32) + ldin(b,po+tid+256,f32);
  float o2 = d2*rstd*ldin(w,po+tid+512,f32) + ldin(b,po+tid+512,f32);
  float* orow = out + (size_t)row*Cc;
  orow[tid]=o0; orow[tid+256]=o1; orow[tid+512]=o2;
  if(outBase){
    size_t o = off0 + (size_t)row*Cc;
    stout(outBase,o+tid    ,o0,f32);
    stout(outBase,o+tid+256,o1,f32);
    stout(outBase,o+tid+512,o2,f32);
  }
}

// ---- GEMM: out[M,N] = A[M,K](f32) @ B[K,N] (+bias)(gelu)(+resid) ----
// B read at element offset bo0, bias at element offset vo0.
// BT=true: B is [N,K] row-major, used transposed (logits head).
// 64x64 tile, BK=16, 256 threads, 4x4/thread. M%64==0, N%64==0, K%16==0.
template<bool BT, bool GELU>
__global__ __launch_bounds__(256) void gemm_kernel(const float* __restrict__ A,
    const void* __restrict__ Bw, size_t bo0,
    const void* __restrict__ bias, size_t vo0,
    const float* __restrict__ resid, float* __restrict__ outF,
    void* __restrict__ outBase, size_t off0, int M, int N, int K,
    const int* flagp){
  int f32 = *flagp;
  __shared__ float As[16][65];
  __shared__ float Bs[16][65];
  int tid = threadIdx.x;
  int n0 = blockIdx.x*64, m0 = blockIdx.y*64;
  int tn = tid & 15, tm = tid >> 4;
  float acc[4][4] = {{0,0,0,0},{0,0,0,0},{0,0,0,0},{0,0,0,0}};

  int am = tid >> 2;          // 0..63
  int ak = (tid & 3) * 4;     // 0,4,8,12
  int bn = (tid & 15) * 4;
  int bk = tid >> 4;

  for(int k0 = 0; k0 < K; k0 += 16){
    float4 av = *(const float4*)(A + (size_t)(m0+am)*K + k0 + ak);
    As[ak+0][am]=av.x; As[ak+1][am]=av.y; As[ak+2][am]=av.z; As[ak+3][am]=av.w;
    if(!BT){
      size_t bo = bo0 + (size_t)(k0+bk)*N + n0 + bn;
      Bs[bk][bn+0]=ldin(Bw,bo+0,f32); Bs[bk][bn+1]=ldin(Bw,bo+1,f32);
      Bs[bk][bn+2]=ldin(Bw,bo+2,f32); Bs[bk][bn+3]=ldin(Bw,bo+3,f32);
    } else {
      size_t bo = bo0 + (size_t)(n0+am)*K + k0 + ak;
      Bs[ak+0][am]=ldin(Bw,bo+0,f32); Bs[ak+1][am]=ldin(Bw,bo+1,f32);
      Bs[ak+2][am]=ldin(Bw,bo+2,f32); Bs[ak+3][am]=ldin(Bw,bo+3,f32);
    }
    __syncthreads();
    #pragma unroll
    for(int kk=0; kk<16; kk++){
      float a[4], bb[4];
      #pragma unroll
      for(int i=0;i<4;i++) a[i]  = As[kk][tm*4+i];
      #pragma unroll
      for(int j=0;j<4;j++) bb[j] = Bs[kk][tn*4+j];
      #pragma unroll
      for(int i=0;i<4;i++)
        #pragma unroll
        for(int j=0;j<4;j++)
          acc[i][j] = fmaf(a[i], bb[j], acc[i][j]);
    }
    __syncthreads();
  }

  #pragma unroll
  for(int i=0;i<4;i++){
    int row = m0 + tm*4 + i;
    #pragma unroll
    for(int j=0;j<4;j++){
      int col = n0 + tn*4 + j;
      float v = acc[i][j];
      if(bias) v += ldin(bias,vo0+col,f32);
      if(GELU) v = 0.5f*v*(1.0f + erff(v*0.70710678118f));
      if(resid) v += resid[(size_t)row*N + col];
      if(outF) outF[(size_t)row*N + col] = v;
      if(outBase) stout(outBase, off0 + (size_t)row*N + col, v, f32);
    }
  }
}

// -------- attention scores + causal softmax, one block per (b,h,qt) row ----
__global__ __launch_bounds__(256) void attn_kernel(const float* __restrict__ q,
    const float* __restrict__ k, void* __restrict__ outBase, size_t off0,
    const int* flagp){
  int f32 = *flagp;
  int bid = blockIdx.x;            // ((b*H + h)*T + qt)
  int qt = bid % Tt;
  int h  = (bid / Tt) % Hh;
  int b  = bid / (Tt*Hh);
  int tid = threadIdx.x;
  __shared__ float sq[HDd];
  __shared__ float red[256];
  if(tid < HDd) sq[tid] = q[(size_t)(b*Tt+qt)*Cc + h*HDd + tid];
  __syncthreads();
  float s[2];
  #pragma unroll
  for(int i=0;i<2;i++){
    int kt = tid + i*256;
    if(kt <= qt){
      const float* kr = k + (size_t)(b*Tt+kt)*Cc + h*HDd;
      float acc = 0.f;
      #pragma unroll
      for(int j=0;j<HDd;j++) acc = fmaf(sq[j], kr[j], acc);
      s[i] = acc * 0.125f;   // 1/sqrt(64)
    } else s[i] = -INFINITY;
  }
  float m = fmaxf(s[0], s[1]);
  red[tid]=m; __syncthreads();
  for(int off=128; off>0; off>>=1){ if(tid<off) red[tid]=fmaxf(red[tid],red[tid+off]); __syncthreads(); }
  m = red[0];
  __syncthreads();
  float e0 = expf(s[0]-m), e1 = expf(s[1]-m);   // exp(-inf)=0 for masked
  red[tid]=e0+e1; __syncthreads();
  for(int off=128; off>0; off>>=1){ if(tid<off) red[tid]+=red[tid+off]; __syncthreads(); }
  float inv = 1.0f/red[0];
  size_t ar = off0 + (size_t)bid*Tt;
  stout(outBase, ar+tid    , e0*inv, f32);
  stout(outBase, ar+tid+256, e1*inv, f32);
}

// -------- y = att @ v  as tiled batched GEMM --------------------------------
// grid = B*H*(T/64) blocks, 256 threads. Each block: 64(qt) x 64(hd) output
// tile for one (b,h); loops causal k-tiles of 64 with att+v staged in LDS.
// Masked att entries are exactly 0.0 in memory, so the diagonal tile's upper
// triangle contributes nothing. 4x4 acc per thread, float4/ushort4 loads.
__global__ __launch_bounds__(256) void av_kernel(const void* __restrict__ attBase,
    size_t off0, const float* __restrict__ v, float* __restrict__ y,
    const int* flagp){
  int f32 = *flagp;
  int bid = blockIdx.x;            // bh*(T/64) + qtile
  int qtile = bid & 7;
  int bh = bid >> 3;
  int h = bh % Hh, b = bh / Hh;
  int qt0 = qtile * 64;
  __shared__ float As[64][68];     // att tile: [q][k], stride 68 (16B aligned)
  __shared__ float Vs[64][68];     // v   tile: [k][hd]
  int tid = threadIdx.x;
  int tn = tid & 15, tm = tid >> 4;
  float acc[4][4] = {{0,0,0,0},{0,0,0,0},{0,0,0,0},{0,0,0,0}};

  int lr = tid >> 2;               // 0..63 tile row
  int lc = (tid & 3) * 16;         // col start (16 elems/thread)
  size_t att0 = off0 + ((size_t)bh*Tt + qt0)*Tt;
  const float* vbase = v + (size_t)b*Tt*Cc + h*HDd;

  for(int k0 = 0; k0 <= qt0; k0 += 64){
    // --- att tile load (bf16 or f32, vectorized) ---
    size_t ao = att0 + (size_t)lr*Tt + k0 + lc;
    if(f32){
      const float4* p = (const float4*)((const float*)attBase + ao);
      #pragma unroll
      for(int u=0;u<4;u++){
        float4 t = p[u];
        As[lr][lc+u*4+0]=t.x; As[lr][lc+u*4+1]=t.y;
        As[lr][lc+u*4+2]=t.z; As[lr][lc+u*4+3]=t.w;
      }
    } else {
      const ushort4* p = (const ushort4*)((const unsigned short*)attBase + ao);
      #pragma unroll
      for(int u=0;u<4;u++){
        ushort4 t = p[u];
        As[lr][lc+u*4+0]=__uint_as_float((unsigned)t.x<<16);
        As[lr][lc+u*4+1]=__uint_as_float((unsigned)t.y<<16);
        As[lr][lc+u*4+2]=__uint_as_float((unsigned)t.z<<16);
        As[lr][lc+u*4+3]=__uint_as_float((unsigned)t.w<<16);
      }
    }
    // --- v tile load (f32 workspace) ---
    const float4* vp = (const float4*)(vbase + (size_t)(k0+lr)*Cc + lc);
    #pragma unroll
    for(int u=0;u<4;u++){
      float4 t = vp[u];
      Vs[lr][lc+u*4+0]=t.x; Vs[lr][lc+u*4+1]=t.y;
      Vs[lr][lc+u*4+2]=t.z; Vs[lr][lc+u*4+3]=t.w;
    }
    __syncthreads();
    #pragma unroll 16
    for(int kk=0; kk<64; kk++){
      float a0=As[tm*4+0][kk], a1=As[tm*4+1][kk],
            a2=As[tm*4+2][kk], a3=As[tm*4+3][kk];
      float4 bv = *(const float4*)&Vs[kk][tn*4];
      acc[0][0]=fmaf(a0,bv.x,acc[0][0]); acc[0][1]=fmaf(a0,bv.y,acc[0][1]);
      acc[0][2]=fmaf(a0,bv.z,acc[0][2]); acc[0][3]=fmaf(a0,bv.w,acc[0][3]);
      acc[1][0]=fmaf(a1,bv.x,acc[1][0]); acc[1][1]=fmaf(a1,bv.y,acc[1][1]);
      acc[1][2]=fmaf(a1,bv.z,acc[1][2]); acc[1][3]=fmaf(a1,bv.w,acc[1][3]);
      acc[2][0]=fmaf(a2,bv.x,acc[2][0]); acc[2][1]=fmaf(a2,bv.y,acc[2][1]);
      acc[2][2]=fmaf(a2,bv.z,acc[2][2]); acc[2][3]=fmaf(a2,bv.w,acc[2][3]);
      acc[3][0]=fmaf(a3,bv.x,acc[3][0]); acc[3][1]=fmaf(a3,bv.y,acc[3][1]);
      acc[3][2]=fmaf(a3,bv.z,acc[3][2]); acc[3][3]=fmaf(a3,bv.w,acc[3][3]);
    }
    __syncthreads();
  }

  #pragma unroll
  for(int i=0;i<4;i++){
    float* yr = y + (size_t)(b*Tt + qt0 + tm*4 + i)*Cc + h*HDd + tn*4;
    *(float4*)yr = make_float4(acc[i][0], acc[i][1], acc[i][2], acc[i][3]);
  }
}

extern "C" void kernel_launch(void* const* d_in, const int* in_sizes, int n_in,
                              void* d_out, int out_size, void* d_ws, size_t ws_size,
                              hipStream_t stream) {
  (void)in_sizes; (void)n_in; (void)out_size; (void)ws_size;
  const int*  idx  = (const int*)d_in[0];
  const void* tok  = d_in[1];
  const void* typ  = d_in[2];
  const void* pos  = d_in[3];
  const void* Wq   = d_in[4];
  const void* bq   = d_in[5];
  const void* Wk   = d_in[6];
  const void* bk   = d_in[7];
  const void* Wv   = d_in[8];
  const void* bv   = d_in[9];
  const void* Wp   = d_in[10];
  const void* bp   = d_in[11];
  const void* ln1w = d_in[12];
  const void* ln1b = d_in[13];
  const void* ln2w = d_in[14];
  const void* ln2b = d_in[15];
  const void* W1   = d_in[16];
  const void* b1   = d_in[17];
  const void* W2   = d_in[18];
  const void* b2   = d_in[19];
  const void* lnfw = d_in[20];
  const void* lnfb = d_in[21];
  const void* headw= d_in[22];

  const size_t NTC = (size_t)Bb*Tt*Cc;        // 1,572,864
  const size_t ATT_L = (size_t)Bb*Hh*Tt*Tt;   // 12,582,912

  float* x  = (float*)d_ws;
  float* h  = x + NTC;
  float* q  = h + NTC;
  float* k  = q + NTC;
  float* v  = k + NTC;
  float* y  = v + NTC;
  float* ff = y + NTC;                        // B*T*FF floats
  int* flag = (int*)(ff + (size_t)Bb*Tt*FFf);

  const size_t offX   = (size_t)Bb*Tt*Vv;     // d_out element offsets
  const size_t offAtt = offX + NTC;

  const int M = Bb*Tt;                        // 2048
  dim3 blk(256);
  dim3 gC(Cc/64,  M/64);
  dim3 gF(FFf/64, M/64);
  dim3 gV(Vv/64,  M/64);

  detect_kernel<<<1, blk, 0, stream>>>(tok, flag);
  embed_kernel<<<(Bb*Tt*Cc)/256, blk, 0, stream>>>(idx, tok, typ, pos, x, flag);

  for(int l=0; l<Ll; l++){
    const size_t wC  = (size_t)l*Cc*Cc;
    const size_t wF1 = (size_t)l*Cc*FFf;
    const size_t wF2 = (size_t)l*FFf*Cc;
    const size_t vC  = (size_t)l*Cc;
    const size_t vF  = (size_t)l*FFf;
    const size_t attOff = offAtt + (size_t)l*ATT_L;

    ln_kernel<<<M, blk, 0, stream>>>(x, ln1w, ln1b, vC, h, nullptr, 0, flag);
    gemm_kernel<false,false><<<gC, blk, 0, stream>>>(h, Wq, wC, bq, vC, nullptr, q, nullptr, 0, M, Cc, Cc, flag);
    gemm_kernel<false,false><<<gC, blk, 0, stream>>>(h, Wk, wC, bk, vC, nullptr, k, nullptr, 0, M, Cc, Cc, flag);
    gemm_kernel<false,false><<<gC, blk, 0, stream>>>(h, Wv, wC, bv, vC, nullptr, v, nullptr, 0, M, Cc, Cc, flag);

    attn_kernel<<<Bb*Hh*Tt, blk, 0, stream>>>(q, k, d_out, attOff, flag);
    av_kernel<<<Bb*Hh*(Tt/64), blk, 0, stream>>>(d_out, attOff, v, y, flag);

    gemm_kernel<false,false><<<gC, blk, 0, stream>>>(y, Wp, wC, bp, vC, x, x, nullptr, 0, M, Cc, Cc, flag);

    ln_kernel<<<M, blk, 0, stream>>>(x, ln2w, ln2b, vC, h, nullptr, 0, flag);
    gemm_kernel<false,true ><<<gF, blk, 0, stream>>>(h, W1, wF1, b1, vF, nullptr, ff, nullptr, 0, M, FFf, Cc, flag);
    gemm_kernel<false,false><<<gC, blk, 0, stream>>>(ff, W2, wF2, b2, vC, x, x, nullptr, 0, M, Cc, FFf, flag);
  }

  ln_kernel<<<M, blk, 0, stream>>>(x, lnfw, lnfb, 0, h, d_out, offX, flag);
  gemm_kernel<true,false><<<gV, blk, 0, stream>>>(h, headw, 0, nullptr, 0, nullptr, nullptr, d_out, 0, M, Vv, Cc, flag);
}

// Round 2
// 3851.127 us; speedup vs baseline: 3.3493x; 2.5840x over previous
//
#include <hip/hip_runtime.h>
#include <hip/hip_bf16.h>
#include <math.h>

// Problem constants
#define Bb 4
#define Tt 512
#define Cc 768
#define Hh 12
#define Ll 8
#define Vv 512
#define FFf 3072
#define HDd 64

typedef __hip_bfloat16 bf16;
typedef unsigned short u16;
typedef __bf16 bfv8 __attribute__((ext_vector_type(8)));
typedef float f32x4 __attribute__((ext_vector_type(4)));

__device__ __forceinline__ float b2f(bf16 x){ return __bfloat162float(x); }
__device__ __forceinline__ bf16 f2b(float x){ return __float2bfloat16(x); }
__device__ __forceinline__ u16 f2bu(float x){
  bf16 b = __float2bfloat16(x);
  return *reinterpret_cast<u16*>(&b);
}
__device__ __forceinline__ float bu2f(u16 u){ return __uint_as_float((unsigned)u<<16); }

// dtype-flexible input load / output store. f32!=0 -> buffers are float32.
__device__ __forceinline__ float ldin(const void* p, size_t i, int f32){
  return f32 ? ((const float*)p)[i] : b2f(((const bf16*)p)[i]);
}
__device__ __forceinline__ void stout(void* p, size_t i, float v, int f32){
  if(f32) ((float*)p)[i] = v; else ((bf16*)p)[i] = f2b(v);
}

// ---------------- dtype detect: scan tok_emb viewed as bf16 ----------------
__global__ __launch_bounds__(256) void detect_kernel(const void* tok, int* flag){
  __shared__ int any;
  int tid = threadIdx.x;
  if(tid==0) any = 0;
  __syncthreads();
  const u16* u = (const u16*)tok;
  int local = 0;
  for(int i = tid; i < 16384; i += 256){
    u16 e = (u[i] >> 7) & 0xFF;
    if(e >= 0x90) local = 1;
  }
  if(local) any = 1;
  __syncthreads();
  if(tid==0) flag[0] = any;                  // 1 => float32 I/O
}

// ---------------- embeddings: x = tok[idx] + pos + type[1] ----------------
__global__ __launch_bounds__(256) void embed_kernel(const int* __restrict__ idx,
    const void* __restrict__ tok, const void* __restrict__ typ,
    const void* __restrict__ pos, float* __restrict__ x, const int* flagp){
  int f32 = *flagp;
  int i = blockIdx.x*256 + threadIdx.x;       // over B*T*C
  int c = i % Cc;
  int bt = i / Cc;
  int t = bt % Tt;
  int row = idx[bt];
  x[i] = ldin(tok,(size_t)row*Cc+c,f32) + ldin(pos,(size_t)t*Cc+c,f32)
       + ldin(typ,(size_t)Cc+c,f32);
}

// -------- weight transpose+cast: W[K,N](dtype) -> out[N,K] bf16 ------------
__global__ __launch_bounds__(256) void transpose_kernel(const void* __restrict__ W,
    size_t wo, u16* __restrict__ out, int K, int N, const int* flagp){
  int f32 = *flagp;
  __shared__ float Ts[32][33];
  int n0 = blockIdx.x*32, k0 = blockIdx.y*32;
  int t = threadIdx.x;
  int r = t>>3, c4 = (t&7)*4;
  size_t gi = wo + (size_t)(k0+r)*N + n0 + c4;
  if(f32){
    float4 v = *(const float4*)((const float*)W + gi);
    Ts[r][c4+0]=v.x; Ts[r][c4+1]=v.y; Ts[r][c4+2]=v.z; Ts[r][c4+3]=v.w;
  } else {
    ushort4 v = *(const ushort4*)((const u16*)W + gi);
    Ts[r][c4+0]=bu2f(v.x); Ts[r][c4+1]=bu2f(v.y);
    Ts[r][c4+2]=bu2f(v.z); Ts[r][c4+3]=bu2f(v.w);
  }
  __syncthreads();
  ushort4 o;
  o.x=f2bu(Ts[c4+0][r]); o.y=f2bu(Ts[c4+1][r]);
  o.z=f2bu(Ts[c4+2][r]); o.w=f2bu(Ts[c4+3][r]);
  *(ushort4*)(out + (size_t)(n0+r)*K + k0 + c4) = o;
}

// -------- head weight cast: W[N,K](dtype) -> out bf16 (layout kept) --------
__global__ __launch_bounds__(256) void conv_kernel(const void* __restrict__ W,
    u16* __restrict__ out, const int* flagp){
  int f32 = *flagp;
  size_t i = ((size_t)blockIdx.x*256 + threadIdx.x)*4;
  if(f32){
    float4 v = *(const float4*)((const float*)W + i);
    ushort4 o = {f2bu(v.x), f2bu(v.y), f2bu(v.z), f2bu(v.w)};
    *(ushort4*)(out + i) = o;
  } else {
    ushort4 v = *(const ushort4*)((const u16*)W + i);
    *(ushort4*)(out + i) = v;
  }
}

// ---------------- LayerNorm over C=768, one block per row ----------------
// Writes h as bf16 (GEMM A operand). Optional dtype mirror to outBase.
__global__ __launch_bounds__(256) void ln_kernel(const float* __restrict__ x,
    const void* __restrict__ w, const void* __restrict__ b, size_t po,
    u16* __restrict__ out, void* __restrict__ outBase, size_t off0,
    const int* flagp){
  int f32 = *flagp;
  int row = blockIdx.x, tid = threadIdx.x;
  const float* xr = x + (size_t)row*Cc;
  float v0=xr[tid], v1=xr[tid+256], v2=xr[tid+512];
  __shared__ float red[256];
  red[tid]=v0+v1+v2; __syncthreads();
  for(int off=128; off>0; off>>=1){ if(tid<off) red[tid]+=red[tid+off]; __syncthreads(); }
  float mean = red[0]*(1.0f/Cc);
  __syncthreads();
  float d0=v0-mean, d1=v1-mean, d2=v2-mean;
  red[tid]=d0*d0+d1*d1+d2*d2; __syncthreads();
  for(int off=128; off>0; off>>=1){ if(tid<off) red[tid]+=red[tid+off]; __syncthreads(); }
  float rstd = rsqrtf(red[0]*(1.0f/Cc) + 1e-5f);
  float o0 = d0*rstd*ldin(w,po+tid    ,f32) + ldin(b,po+tid    ,f32);
  float o1 = d1*rstd*ldin(w,po+tid+256,f32) + ldin(b,po+tid+256,f32);
  float o2 = d2*rstd*ldin(w,po+tid+512,f32) + ldin(b,po+tid+512,f32);
  u16* orow = out + (size_t)row*Cc;
  orow[tid]=f2bu(o0); orow[tid+256]=f2bu(o1); orow[tid+512]=f2bu(o2);
  if(outBase){
    size_t o = off0 + (size_t)row*Cc;
    stout(outBase,o+tid    ,o0,f32);
    stout(outBase,o+tid+256,o1,f32);
    stout(outBase,o+tid+512,o2,f32);
  }
}

// ---- MFMA GEMM: out[M,N] = A[M,K](bf16) @ Bt[N,K](bf16)^T ----------------
// Wave-tile FIx16 x FJx16, wave grid WR x WC, block = 256 thr = 4 waves.
// BK=64, XOR-swizzled LDS (chunk^=(row&7)) -> conflict-light ds_read_b128.
// Epilogue: +bias, GELU, +resid(f32), out to f32 or bf16 (OUTBF) and/or
// dtype outBase at off0.
template<int WR,int WC,int FI,int FJ,bool GELU_,bool OUTBF>
__global__ __launch_bounds__(256) void gemm_mfma(const u16* __restrict__ A,
    const u16* __restrict__ Bt, const void* __restrict__ bias, size_t vo0,
    const float* __restrict__ resid, void* __restrict__ outF,
    void* __restrict__ outBase, size_t off0, int N, int K, const int* flagp){
  constexpr int BM = WR*FI*16, BN = WC*FJ*16;
  int f32 = *flagp;
  __shared__ u16 As[BM*64];
  __shared__ u16 Bs[BN*64];
  int tid = threadIdx.x;
  int lane = tid & 63, wid = tid >> 6;
  int wr = wid / WC, wc = wid % WC;
  int n0 = blockIdx.x*BN, m0 = blockIdx.y*BM;
  f32x4 acc[FI][FJ];
  #pragma unroll
  for(int i=0;i<FI;i++)
    #pragma unroll
    for(int j=0;j<FJ;j++)
      #pragma unroll
      for(int q=0;q<4;q++) acc[i][j][q]=0.f;

  constexpr int CHA = BM/32;   // uint4 chunks per thread (A)
  constexpr int CHB = BN/32;   // uint4 chunks per thread (B)
  int rA0 = wr*(FI*16) + (lane&15);
  int rB0 = wc*(FJ*16) + (lane&15);
  int cg = lane>>4;            // 0..3 k-group of this lane

  for(int k0=0; k0<K; k0+=64){
    #pragma unroll
    for(int i=0;i<CHA;i++){
      int lin = tid*CHA + i;
      int row = lin>>3, c = lin&7;
      uint4 w = *(const uint4*)(A + (size_t)(m0+row)*K + k0 + c*8);
      *(uint4*)&As[row*64 + ((c ^ (row&7))<<3)] = w;
    }
    #pragma unroll
    for(int i=0;i<CHB;i++){
      int lin = tid*CHB + i;
      int row = lin>>3, c = lin&7;
      uint4 w = *(const uint4*)(Bt + (size_t)(n0+row)*K + k0 + c*8);
      *(uint4*)&Bs[row*64 + ((c ^ (row&7))<<3)] = w;
    }
    __syncthreads();
    #pragma unroll
    for(int ks=0; ks<2; ks++){
      bfv8 af[FI], bf_[FJ];
      int c = ks*4 + cg;
      #pragma unroll
      for(int i=0;i<FI;i++){ int row=rA0+i*16; af[i] = *(bfv8*)&As[row*64 + ((c^(row&7))<<3)]; }
      #pragma unroll
      for(int j=0;j<FJ;j++){ int row=rB0+j*16; bf_[j] = *(bfv8*)&Bs[row*64 + ((c^(row&7))<<3)]; }
      #pragma unroll
      for(int i=0;i<FI;i++)
        #pragma unroll
        for(int j=0;j<FJ;j++)
          acc[i][j] = __builtin_amdgcn_mfma_f32_16x16x32_bf16(af[i], bf_[j], acc[i][j], 0, 0, 0);
    }
    __syncthreads();
  }

  // C/D layout: col = lane&15, row = (lane>>4)*4 + reg   [m89/m91]
  int rowb = m0 + wr*FI*16 + (lane>>4)*4;
  int colb = n0 + wc*FJ*16 + (lane&15);
  #pragma unroll
  for(int j=0;j<FJ;j++){
    int col = colb + j*16;
    float bval = bias ? ldin(bias, vo0+col, f32) : 0.f;
    #pragma unroll
    for(int i=0;i<FI;i++){
      #pragma unroll
      for(int r=0;r<4;r++){
        int row = rowb + i*16 + r;
        float val = acc[i][j][r] + bval;
        if(GELU_) val = 0.5f*val*(1.0f + erff(val*0.70710678118f));
        if(resid) val += resid[(size_t)row*N + col];
        if(outF){
          if(OUTBF) ((u16*)outF)[(size_t)row*N + col] = f2bu(val);
          else      ((float*)outF)[(size_t)row*N + col] = val;
        }
        if(outBase) stout(outBase, off0 + (size_t)row*N + col, val, f32);
      }
    }
  }
}

// -------- attention scores + causal softmax, one block per (b,h,qt) row ----
__global__ __launch_bounds__(256) void attn_kernel(const float* __restrict__ q,
    const float* __restrict__ k, void* __restrict__ outBase, size_t off0,
    const int* flagp){
  int f32 = *flagp;
  int bid = blockIdx.x;            // ((b*H + h)*T + qt)
  int qt = bid % Tt;
  int h  = (bid / Tt) % Hh;
  int b  = bid / (Tt*Hh);
  int tid = threadIdx.x;
  __shared__ float sq[HDd];
  __shared__ float red[256];
  if(tid < HDd) sq[tid] = q[(size_t)(b*Tt+qt)*Cc + h*HDd + tid];
  __syncthreads();
  float s[2];
  #pragma unroll
  for(int i=0;i<2;i++){
    int kt = tid + i*256;
    if(kt <= qt){
      const float* kr = k + (size_t)(b*Tt+kt)*Cc + h*HDd;
      float acc = 0.f;
      #pragma unroll
      for(int j=0;j<HDd;j++) acc = fmaf(sq[j], kr[j], acc);
      s[i] = acc * 0.125f;   // 1/sqrt(64)
    } else s[i] = -INFINITY;
  }
  float m = fmaxf(s[0], s[1]);
  red[tid]=m; __syncthreads();
  for(int off=128; off>0; off>>=1){ if(tid<off) red[tid]=fmaxf(red[tid],red[tid+off]); __syncthreads(); }
  m = red[0];
  __syncthreads();
  float e0 = expf(s[0]-m), e1 = expf(s[1]-m);   // exp(-inf)=0 for masked
  red[tid]=e0+e1; __syncthreads();
  for(int off=128; off>0; off>>=1){ if(tid<off) red[tid]+=red[tid+off]; __syncthreads(); }
  float inv = 1.0f/red[0];
  size_t ar = off0 + (size_t)bid*Tt;
  stout(outBase, ar+tid    , e0*inv, f32);
  stout(outBase, ar+tid+256, e1*inv, f32);
}

// -------- y = att @ v  as tiled batched GEMM, y written bf16 ---------------
__global__ __launch_bounds__(256) void av_kernel(const void* __restrict__ attBase,
    size_t off0, const float* __restrict__ v, u16* __restrict__ y,
    const int* flagp){
  int f32 = *flagp;
  int bid = blockIdx.x;            // bh*(T/64) + qtile
  int qtile = bid & 7;
  int bh = bid >> 3;
  int h = bh % Hh, b = bh / Hh;
  int qt0 = qtile * 64;
  __shared__ float As[64][68];     // att tile: [q][k]
  __shared__ float Vs[64][68];     // v   tile: [k][hd]
  int tid = threadIdx.x;
  int tn = tid & 15, tm = tid >> 4;
  float acc[4][4] = {{0,0,0,0},{0,0,0,0},{0,0,0,0},{0,0,0,0}};

  int lr = tid >> 2;               // 0..63 tile row
  int lc = (tid & 3) * 16;         // col start (16 elems/thread)
  size_t att0 = off0 + ((size_t)bh*Tt + qt0)*Tt;
  const float* vbase = v + (size_t)b*Tt*Cc + h*HDd;

  for(int k0 = 0; k0 <= qt0; k0 += 64){
    size_t ao = att0 + (size_t)lr*Tt + k0 + lc;
    if(f32){
      const float4* p = (const float4*)((const float*)attBase + ao);
      #pragma unroll
      for(int u=0;u<4;u++){
        float4 t = p[u];
        As[lr][lc+u*4+0]=t.x; As[lr][lc+u*4+1]=t.y;
        As[lr][lc+u*4+2]=t.z; As[lr][lc+u*4+3]=t.w;
      }
    } else {
      const ushort4* p = (const ushort4*)((const u16*)attBase + ao);
      #pragma unroll
      for(int u=0;u<4;u++){
        ushort4 t = p[u];
        As[lr][lc+u*4+0]=bu2f(t.x); As[lr][lc+u*4+1]=bu2f(t.y);
        As[lr][lc+u*4+2]=bu2f(t.z); As[lr][lc+u*4+3]=bu2f(t.w);
      }
    }
    const float4* vp = (const float4*)(vbase + (size_t)(k0+lr)*Cc + lc);
    #pragma unroll
    for(int u=0;u<4;u++){
      float4 t = vp[u];
      Vs[lr][lc+u*4+0]=t.x; Vs[lr][lc+u*4+1]=t.y;
      Vs[lr][lc+u*4+2]=t.z; Vs[lr][lc+u*4+3]=t.w;
    }
    __syncthreads();
    #pragma unroll 16
    for(int kk=0; kk<64; kk++){
      float a0=As[tm*4+0][kk], a1=As[tm*4+1][kk],
            a2=As[tm*4+2][kk], a3=As[tm*4+3][kk];
      float4 bv = *(const float4*)&Vs[kk][tn*4];
      acc[0][0]=fmaf(a0,bv.x,acc[0][0]); acc[0][1]=fmaf(a0,bv.y,acc[0][1]);
      acc[0][2]=fmaf(a0,bv.z,acc[0][2]); acc[0][3]=fmaf(a0,bv.w,acc[0][3]);
      acc[1][0]=fmaf(a1,bv.x,acc[1][0]); acc[1][1]=fmaf(a1,bv.y,acc[1][1]);
      acc[1][2]=fmaf(a1,bv.z,acc[1][2]); acc[1][3]=fmaf(a1,bv.w,acc[1][3]);
      acc[2][0]=fmaf(a2,bv.x,acc[2][0]); acc[2][1]=fmaf(a2,bv.y,acc[2][1]);
      acc[2][2]=fmaf(a2,bv.z,acc[2][2]); acc[2][3]=fmaf(a2,bv.w,acc[2][3]);
      acc[3][0]=fmaf(a3,bv.x,acc[3][0]); acc[3][1]=fmaf(a3,bv.y,acc[3][1]);
      acc[3][2]=fmaf(a3,bv.z,acc[3][2]); acc[3][3]=fmaf(a3,bv.w,acc[3][3]);
    }
    __syncthreads();
  }

  #pragma unroll
  for(int i=0;i<4;i++){
    ushort4 o = {f2bu(acc[i][0]), f2bu(acc[i][1]), f2bu(acc[i][2]), f2bu(acc[i][3])};
    *(ushort4*)(y + (size_t)(b*Tt + qt0 + tm*4 + i)*Cc + h*HDd + tn*4) = o;
  }
}

extern "C" void kernel_launch(void* const* d_in, const int* in_sizes, int n_in,
                              void* d_out, int out_size, void* d_ws, size_t ws_size,
                              hipStream_t stream) {
  (void)in_sizes; (void)n_in; (void)out_size; (void)ws_size;
  const int*  idx  = (const int*)d_in[0];
  const void* tok  = d_in[1];
  const void* typ  = d_in[2];
  const void* pos  = d_in[3];
  const void* Wq   = d_in[4];
  const void* bq   = d_in[5];
  const void* Wk   = d_in[6];
  const void* bk   = d_in[7];
  const void* Wv   = d_in[8];
  const void* bv   = d_in[9];
  const void* Wp   = d_in[10];
  const void* bp   = d_in[11];
  const void* ln1w = d_in[12];
  const void* ln1b = d_in[13];
  const void* ln2w = d_in[14];
  const void* ln2b = d_in[15];
  const void* W1   = d_in[16];
  const void* b1   = d_in[17];
  const void* W2   = d_in[18];
  const void* b2   = d_in[19];
  const void* lnfw = d_in[20];
  const void* lnfb = d_in[21];
  const void* headw= d_in[22];

  const size_t NTC = (size_t)Bb*Tt*Cc;        // 1,572,864
  const size_t ATT_L = (size_t)Bb*Hh*Tt*Tt;   // 12,582,912
  const size_t CC  = (size_t)Cc*Cc;           // 589,824

  float* x = (float*)d_ws;
  float* q = x + NTC;
  float* k = q + NTC;
  float* v = k + NTC;
  u16* h  = (u16*)(v + NTC);                  // bf16 activations (GEMM A)
  u16* y  = h + NTC;
  u16* ff = y + NTC;                          // B*T*FF bf16
  u16* wt = ff + (size_t)Bb*Tt*FFf;           // per-layer transposed weights
  u16* hw = wt + (4*CC + 2*(size_t)Cc*FFf);   // head weight bf16
  int* flag = (int*)(hw + (size_t)Vv*Cc);

  u16* wqT = wt;
  u16* wkT = wt + CC;
  u16* wvT = wt + 2*CC;
  u16* wpT = wt + 3*CC;
  u16* w1T = wt + 4*CC;                       // [FF, C]
  u16* w2T = w1T + (size_t)Cc*FFf;            // [C, FF]

  const size_t offX   = (size_t)Bb*Tt*Vv;     // d_out element offsets
  const size_t offAtt = offX + NTC;

  const int M = Bb*Tt;                        // 2048
  dim3 blk(256);
  dim3 gQ(Cc/128,  M/64);                     // 64x128-tile GEMMs (N=768)
  dim3 gH(Vv/128,  M/64);                     // head (N=512)
  dim3 gF1(FFf/128, M/128);                   // 128x128 (N=3072)
  dim3 gTc(Cc/32, Cc/32);
  dim3 gT1(FFf/32, Cc/32);
  dim3 gT2(Cc/32, FFf/32);

  detect_kernel<<<1, blk, 0, stream>>>(tok, flag);
  embed_kernel<<<(Bb*Tt*Cc)/256, blk, 0, stream>>>(idx, tok, typ, pos, x, flag);
  conv_kernel<<<((Vv*Cc)/4)/256, blk, 0, stream>>>(headw, hw, flag);

  for(int l=0; l<Ll; l++){
    const size_t vC  = (size_t)l*Cc;
    const size_t vF  = (size_t)l*FFf;
    const size_t attOff = offAtt + (size_t)l*ATT_L;

    transpose_kernel<<<gTc, blk, 0, stream>>>(Wq, (size_t)l*CC, wqT, Cc, Cc, flag);
    transpose_kernel<<<gTc, blk, 0, stream>>>(Wk, (size_t)l*CC, wkT, Cc, Cc, flag);
    transpose_kernel<<<gTc, blk, 0, stream>>>(Wv, (size_t)l*CC, wvT, Cc, Cc, flag);
    transpose_kernel<<<gTc, blk, 0, stream>>>(Wp, (size_t)l*CC, wpT, Cc, Cc, flag);
    transpose_kernel<<<gT1, blk, 0, stream>>>(W1, (size_t)l*Cc*FFf, w1T, Cc, FFf, flag);
    transpose_kernel<<<gT2, blk, 0, stream>>>(W2, (size_t)l*FFf*Cc, w2T, FFf, Cc, flag);

    ln_kernel<<<M, blk, 0, stream>>>(x, ln1w, ln1b, vC, h, nullptr, 0, flag);
    gemm_mfma<1,4,4,2,false,false><<<gQ, blk, 0, stream>>>(h, wqT, bq, vC, nullptr, q, nullptr, 0, Cc, Cc, flag);
    gemm_mfma<1,4,4,2,false,false><<<gQ, blk, 0, stream>>>(h, wkT, bk, vC, nullptr, k, nullptr, 0, Cc, Cc, flag);
    gemm_mfma<1,4,4,2,false,false><<<gQ, blk, 0, stream>>>(h, wvT, bv, vC, nullptr, v, nullptr, 0, Cc, Cc, flag);

    attn_kernel<<<Bb*Hh*Tt, blk, 0, stream>>>(q, k, d_out, attOff, flag);
    av_kernel<<<Bb*Hh*(Tt/64), blk, 0, stream>>>(d_out, attOff, v, y, flag);

    gemm_mfma<1,4,4,2,false,false><<<gQ, blk, 0, stream>>>(y, wpT, bp, vC, x, x, nullptr, 0, Cc, Cc, flag);

    ln_kernel<<<M, blk, 0, stream>>>(x, ln2w, ln2b, vC, h, nullptr, 0, flag);
    gemm_mfma<2,2,4,4,true,true><<<gF1, blk, 0, stream>>>(h, w1T, b1, vF, nullptr, ff, nullptr, 0, FFf, Cc, flag);
    gemm_mfma<1,4,4,2,false,false><<<gQ, blk, 0, stream>>>(ff, w2T, b2, vC, x, x, nullptr, 0, Cc, FFf, flag);
  }

  ln_kernel<<<M, blk, 0, stream>>>(x, lnfw, lnfb, 0, h, d_out, offX, flag);
  gemm_mfma<1,4,4,2,false,false><<<gH, blk, 0, stream>>>(h, hw, nullptr, 0, nullptr, nullptr, d_out, 0, Vv, Cc, flag);
}

// Round 3
// 1925.185 us; speedup vs baseline: 6.7000x; 2.0004x over previous
//
#include <hip/hip_runtime.h>
#include <hip/hip_bf16.h>
#include <math.h>

// Problem constants
#define Bb 4
#define Tt 512
#define Cc 768
#define Hh 12
#define Ll 8
#define Vv 512
#define FFf 3072
#define HDd 64

typedef __hip_bfloat16 bf16;
typedef unsigned short u16;
typedef __bf16 bfv8 __attribute__((ext_vector_type(8)));
typedef float f32x4 __attribute__((ext_vector_type(4)));

#define SCL 0.18033688f   // 0.125 * log2(e): softmax scale folded into exp2

__device__ __forceinline__ float b2f(bf16 x){ return __bfloat162float(x); }
__device__ __forceinline__ bf16 f2b(float x){ return __float2bfloat16(x); }
__device__ __forceinline__ u16 f2bu(float x){
  bf16 b = __float2bfloat16(x);
  return *reinterpret_cast<u16*>(&b);
}
__device__ __forceinline__ float bu2f(u16 u){ return __uint_as_float((unsigned)u<<16); }

// dtype-flexible input load / output store. f32!=0 -> buffers are float32.
__device__ __forceinline__ float ldin(const void* p, size_t i, int f32){
  return f32 ? ((const float*)p)[i] : b2f(((const bf16*)p)[i]);
}
__device__ __forceinline__ void stout(void* p, size_t i, float v, int f32){
  if(f32) ((float*)p)[i] = v; else ((bf16*)p)[i] = f2b(v);
}

// ---------------- dtype detect: scan tok_emb viewed as bf16 ----------------
__global__ __launch_bounds__(256) void detect_kernel(const void* tok, int* flag){
  __shared__ int any;
  int tid = threadIdx.x;
  if(tid==0) any = 0;
  __syncthreads();
  const u16* u = (const u16*)tok;
  int local = 0;
  for(int i = tid; i < 16384; i += 256){
    u16 e = (u[i] >> 7) & 0xFF;
    if(e >= 0x90) local = 1;
  }
  if(local) any = 1;
  __syncthreads();
  if(tid==0) flag[0] = any;                  // 1 => float32 I/O
}

// ---------------- embeddings: x = tok[idx] + pos + type[1] ----------------
__global__ __launch_bounds__(256) void embed_kernel(const int* __restrict__ idx,
    const void* __restrict__ tok, const void* __restrict__ typ,
    const void* __restrict__ pos, float* __restrict__ x, const int* flagp){
  int f32 = *flagp;
  int i = blockIdx.x*256 + threadIdx.x;       // over B*T*C
  int c = i % Cc;
  int bt = i / Cc;
  int t = bt % Tt;
  int row = idx[bt];
  x[i] = ldin(tok,(size_t)row*Cc+c,f32) + ldin(pos,(size_t)t*Cc+c,f32)
       + ldin(typ,(size_t)Cc+c,f32);
}

// -------- head weight cast: W[N,K](dtype) -> out bf16 (layout kept) --------
__global__ __launch_bounds__(256) void conv_kernel(const void* __restrict__ W,
    u16* __restrict__ out, const int* flagp){
  int f32 = *flagp;
  size_t i = ((size_t)blockIdx.x*256 + threadIdx.x)*4;
  if(f32){
    float4 v = *(const float4*)((const float*)W + i);
    ushort4 o = {f2bu(v.x), f2bu(v.y), f2bu(v.z), f2bu(v.w)};
    *(ushort4*)(out + i) = o;
  } else {
    ushort4 v = *(const ushort4*)((const u16*)W + i);
    *(ushort4*)(out + i) = v;
  }
}

// -------- pack qkv bias [L][2304] in flag dtype ----------------------------
__global__ __launch_bounds__(256) void packb_kernel(const void* __restrict__ bq,
    const void* __restrict__ bk, const void* __restrict__ bv,
    void* __restrict__ out, const int* flagp){
  int f32 = *flagp;
  int i = blockIdx.x*256 + threadIdx.x;     // over L*2304 (=18432, exact grid)
  int lay = i / 2304, c = i % 2304;
  float v;
  if(c < 768)       v = ldin(bq, (size_t)lay*Cc + c,        f32);
  else if(c < 1536) v = ldin(bk, (size_t)lay*Cc + c - 768,  f32);
  else              v = ldin(bv, (size_t)lay*Cc + c - 1536, f32);
  stout(out, i, v, f32);
}

// -------- fused per-layer weight transpose+cast ---------------------------
// Wq/Wk/Wv -> wqkvT [2304][768]; Wp -> wpT [768][768];
// W1[768,3072] -> w1T [3072][768]; W2[3072,768] -> w2T [768][3072].
__global__ __launch_bounds__(256) void transpose_all(const void* __restrict__ Wq,
    const void* __restrict__ Wk, const void* __restrict__ Wv,
    const void* __restrict__ Wp, const void* __restrict__ W1,
    const void* __restrict__ W2, int lay,
    u16* __restrict__ wqkvT, u16* __restrict__ wpT,
    u16* __restrict__ w1T, u16* __restrict__ w2T, const int* flagp){
  int f32 = *flagp;
  int bidx = blockIdx.x;
  const void* src; size_t so; u16* dst; int N, dstLd, nOff, n0, k0;
  if(bidx < 1728){              // Wq/Wk/Wv
    int sec = bidx / 576, lb = bidx % 576;
    src = sec==0?Wq:(sec==1?Wk:Wv);
    so = (size_t)lay*Cc*Cc; N=Cc; dst=wqkvT; dstLd=Cc; nOff = sec*Cc;
    n0 = (lb%24)*32; k0 = (lb/24)*32;
  } else if(bidx < 2304){       // Wp
    int lb = bidx - 1728;
    src=Wp; so=(size_t)lay*Cc*Cc; N=Cc; dst=wpT; dstLd=Cc; nOff=0;
    n0 = (lb%24)*32; k0 = (lb/24)*32;
  } else if(bidx < 4608){       // W1
    int lb = bidx - 2304;
    src=W1; so=(size_t)lay*Cc*FFf; N=FFf; dst=w1T; dstLd=Cc; nOff=0;
    n0 = (lb%96)*32; k0 = (lb/96)*32;
  } else {                      // W2
    int lb = bidx - 4608;
    src=W2; so=(size_t)lay*FFf*Cc; N=Cc; dst=w2T; dstLd=FFf; nOff=0;
    n0 = (lb%24)*32; k0 = (lb/24)*32;
  }
  __shared__ float Ts[32][33];
  int t = threadIdx.x;
  int r = t>>3, c4 = (t&7)*4;
  size_t gi = so + (size_t)(k0+r)*N + n0 + c4;
  if(f32){
    float4 v = *(const float4*)((const float*)src + gi);
    Ts[r][c4+0]=v.x; Ts[r][c4+1]=v.y; Ts[r][c4+2]=v.z; Ts[r][c4+3]=v.w;
  } else {
    ushort4 v = *(const ushort4*)((const u16*)src + gi);
    Ts[r][c4+0]=bu2f(v.x); Ts[r][c4+1]=bu2f(v.y);
    Ts[r][c4+2]=bu2f(v.z); Ts[r][c4+3]=bu2f(v.w);
  }
  __syncthreads();
  ushort4 o;
  o.x=f2bu(Ts[c4+0][r]); o.y=f2bu(Ts[c4+1][r]);
  o.z=f2bu(Ts[c4+2][r]); o.w=f2bu(Ts[c4+3][r]);
  *(ushort4*)(dst + (size_t)(nOff + n0 + r)*dstLd + k0 + c4) = o;
}

// ---------------- LayerNorm over C=768, one block per row ----------------
__global__ __launch_bounds__(256) void ln_kernel(const float* __restrict__ x,
    const void* __restrict__ w, const void* __restrict__ b, size_t po,
    u16* __restrict__ out, void* __restrict__ outBase, size_t off0,
    const int* flagp){
  int f32 = *flagp;
  int row = blockIdx.x, tid = threadIdx.x;
  const float* xr = x + (size_t)row*Cc;
  float v0=xr[tid], v1=xr[tid+256], v2=xr[tid+512];
  __shared__ float red[256];
  red[tid]=v0+v1+v2; __syncthreads();
  for(int off=128; off>0; off>>=1){ if(tid<off) red[tid]+=red[tid+off]; __syncthreads(); }
  float mean = red[0]*(1.0f/Cc);
  __syncthreads();
  float d0=v0-mean, d1=v1-mean, d2=v2-mean;
  red[tid]=d0*d0+d1*d1+d2*d2; __syncthreads();
  for(int off=128; off>0; off>>=1){ if(tid<off) red[tid]+=red[tid+off]; __syncthreads(); }
  float rstd = rsqrtf(red[0]*(1.0f/Cc) + 1e-5f);
  float o0 = d0*rstd*ldin(w,po+tid    ,f32) + ldin(b,po+tid    ,f32);
  float o1 = d1*rstd*ldin(w,po+tid+256,f32) + ldin(b,po+tid+256,f32);
  float o2 = d2*rstd*ldin(w,po+tid+512,f32) + ldin(b,po+tid+512,f32);
  u16* orow = out + (size_t)row*Cc;
  orow[tid]=f2bu(o0); orow[tid+256]=f2bu(o1); orow[tid+512]=f2bu(o2);
  if(outBase){
    size_t o = off0 + (size_t)row*Cc;
    stout(outBase,o+tid    ,o0,f32);
    stout(outBase,o+tid+256,o1,f32);
    stout(outBase,o+tid+512,o2,f32);
  }
}

// ---- MFMA GEMM: out[M,N] = A[M,K](bf16) @ Bt[N,K](bf16)^T ----------------
template<int WR,int WC,int FI,int FJ,bool GELU_,bool OUTBF>
__global__ __launch_bounds__(256) void gemm_mfma(const u16* __restrict__ A,
    const u16* __restrict__ Bt, const void* __restrict__ bias, size_t vo0,
    const float* __restrict__ resid, void* __restrict__ outF,
    void* __restrict__ outBase, size_t off0, int N, int K, const int* flagp){
  constexpr int BM = WR*FI*16, BN = WC*FJ*16;
  int f32 = *flagp;
  __shared__ u16 As[BM*64];
  __shared__ u16 Bs[BN*64];
  int tid = threadIdx.x;
  int lane = tid & 63, wid = tid >> 6;
  int wr = wid / WC, wc = wid % WC;
  int n0 = blockIdx.x*BN, m0 = blockIdx.y*BM;
  f32x4 acc[FI][FJ];
  #pragma unroll
  for(int i=0;i<FI;i++)
    #pragma unroll
    for(int j=0;j<FJ;j++)
      #pragma unroll
      for(int q=0;q<4;q++) acc[i][j][q]=0.f;

  constexpr int CHA = BM/32;
  constexpr int CHB = BN/32;
  int rA0 = wr*(FI*16) + (lane&15);
  int rB0 = wc*(FJ*16) + (lane&15);
  int cg = lane>>4;

  for(int k0=0; k0<K; k0+=64){
    #pragma unroll
    for(int i=0;i<CHA;i++){
      int lin = tid*CHA + i;
      int row = lin>>3, c = lin&7;
      uint4 w = *(const uint4*)(A + (size_t)(m0+row)*K + k0 + c*8);
      *(uint4*)&As[row*64 + ((c ^ (row&7))<<3)] = w;
    }
    #pragma unroll
    for(int i=0;i<CHB;i++){
      int lin = tid*CHB + i;
      int row = lin>>3, c = lin&7;
      uint4 w = *(const uint4*)(Bt + (size_t)(n0+row)*K + k0 + c*8);
      *(uint4*)&Bs[row*64 + ((c ^ (row&7))<<3)] = w;
    }
    __syncthreads();
    #pragma unroll
    for(int ks=0; ks<2; ks++){
      bfv8 af[FI], bf_[FJ];
      int c = ks*4 + cg;
      #pragma unroll
      for(int i=0;i<FI;i++){ int row=rA0+i*16; af[i] = *(bfv8*)&As[row*64 + ((c^(row&7))<<3)]; }
      #pragma unroll
      for(int j=0;j<FJ;j++){ int row=rB0+j*16; bf_[j] = *(bfv8*)&Bs[row*64 + ((c^(row&7))<<3)]; }
      #pragma unroll
      for(int i=0;i<FI;i++)
        #pragma unroll
        for(int j=0;j<FJ;j++)
          acc[i][j] = __builtin_amdgcn_mfma_f32_16x16x32_bf16(af[i], bf_[j], acc[i][j], 0, 0, 0);
    }
    __syncthreads();
  }

  // C/D layout: col = lane&15, row = (lane>>4)*4 + reg
  int rowb = m0 + wr*FI*16 + (lane>>4)*4;
  int colb = n0 + wc*FJ*16 + (lane&15);
  #pragma unroll
  for(int j=0;j<FJ;j++){
    int col = colb + j*16;
    float bval = bias ? ldin(bias, vo0+col, f32) : 0.f;
    #pragma unroll
    for(int i=0;i<FI;i++){
      #pragma unroll
      for(int r=0;r<4;r++){
        int row = rowb + i*16 + r;
        float val = acc[i][j][r] + bval;
        if(GELU_) val = 0.5f*val*(1.0f + erff(val*0.70710678118f));
        if(resid) val += resid[(size_t)row*N + col];
        if(outF){
          if(OUTBF) ((u16*)outF)[(size_t)row*N + col] = f2bu(val);
          else      ((float*)outF)[(size_t)row*N + col] = val;
        }
        if(outBase) stout(outBase, off0 + (size_t)row*N + col, val, f32);
      }
    }
  }
}

// ---------------- fused MFMA attention ------------------------------------
// Block = (b,h,qtile of 64 rows), 4 waves (16 q rows each). Two-phase:
// phase1 computes row max/denominator via QK^T MFMA + shfl reduction;
// phase2 recomputes S, P=exp*inv (bf16), writes att map, accumulates PV.
// qkv: [B*T][2304] bf16 (q|k|v). y: [B*T][768] bf16.
__global__ __launch_bounds__(256) void fattn_kernel(const u16* __restrict__ qkv,
    void* __restrict__ attB, size_t attOff, u16* __restrict__ y,
    const int* flagp){
  int f32 = *flagp;
  int bid = blockIdx.x;
  int qtile = bid & 7;
  int bh = bid >> 3;
  int h = bh % Hh, b = bh / Hh;
  int tid = threadIdx.x;
  int lane = tid & 63, wid = tid >> 6;
  int cl = lane & 15, g = lane >> 4;

  __shared__ u16 Kt[4096];        // [kt][d] swizzled
  __shared__ u16 Vt[4096];        // [d][kt] swizzled (transposed)
  __shared__ u16 Ps[4][1024];     // per-wave P [q16][kt64] swizzled

  // q fragment: A operand rows = cl, d chunks = g*8 (+32 per ks)
  int qg = qtile*64 + wid*16 + cl;
  const u16* qp = qkv + ((size_t)(b*Tt) + qg)*2304 + h*64;
  bfv8 qf0 = *(const bfv8*)(qp + g*8);
  bfv8 qf1 = *(const bfv8*)(qp + 32 + g*8);

  const u16* kbase = qkv + (size_t)(b*Tt)*2304 + 768  + h*64;
  const u16* vbase = qkv + (size_t)(b*Tt)*2304 + 1536 + h*64;

  float m[4], l[4];
  #pragma unroll
  for(int r=0;r<4;r++){ m[r]=-INFINITY; l[r]=0.f; }

  // ---------------- phase 1: stats ----------------
  for(int t=0; t<=qtile; ++t){
    __syncthreads();
    #pragma unroll
    for(int i=0;i<2;i++){
      int u = tid*2 + i;
      int kt = u >> 3, dc = u & 7;
      uint4 w = *(const uint4*)(kbase + (size_t)(t*64+kt)*2304 + dc*8);
      *(uint4*)((char*)Kt + kt*128 + ((dc*16) ^ ((kt&7)<<4))) = w;
    }
    __syncthreads();
    f32x4 sacc[4];
    #pragma unroll
    for(int j=0;j<4;j++)
      #pragma unroll
      for(int r=0;r<4;r++) sacc[j][r]=0.f;
    #pragma unroll
    for(int ks=0; ks<2; ks++){
      bfv8 kb[4];
      #pragma unroll
      for(int j=0;j<4;j++){
        int kr = j*16 + cl;
        kb[j] = *(const bfv8*)((const char*)Kt + kr*128 + ((ks*64 + g*16) ^ ((kr&7)<<4)));
      }
      bfv8 qa = ks ? qf1 : qf0;
      #pragma unroll
      for(int j=0;j<4;j++)
        sacc[j] = __builtin_amdgcn_mfma_f32_16x16x32_bf16(qa, kb[j], sacc[j], 0, 0, 0);
    }
    if(t == qtile){
      #pragma unroll
      for(int j=0;j<4;j++)
        #pragma unroll
        for(int r=0;r<4;r++)
          if(cl + 16*j > wid*16 + g*4 + r) sacc[j][r] = -INFINITY;
    }
    #pragma unroll
    for(int r=0;r<4;r++){
      float tm = fmaxf(fmaxf(sacc[0][r],sacc[1][r]), fmaxf(sacc[2][r],sacc[3][r]));
      #pragma unroll
      for(int mk=1; mk<16; mk<<=1) tm = fmaxf(tm, __shfl_xor(tm, mk, 64));
      float nm = fmaxf(m[r], tm);
      float ps = exp2f(SCL*(sacc[0][r]-nm)) + exp2f(SCL*(sacc[1][r]-nm))
               + exp2f(SCL*(sacc[2][r]-nm)) + exp2f(SCL*(sacc[3][r]-nm));
      #pragma unroll
      for(int mk=1; mk<16; mk<<=1) ps += __shfl_xor(ps, mk, 64);
      l[r] = l[r]*exp2f(SCL*(m[r]-nm)) + ps;
      m[r] = nm;
    }
  }

  float inv[4];
  #pragma unroll
  for(int r=0;r<4;r++) inv[r] = 1.0f / l[r];

  f32x4 oacc[4];
  #pragma unroll
  for(int j=0;j<4;j++)
    #pragma unroll
    for(int r=0;r<4;r++) oacc[j][r]=0.f;

  // ---------------- phase 2: P + att write + PV ----------------
  u16* pr = Ps[wid];
  for(int t=0; t<=qtile; ++t){
    __syncthreads();
    #pragma unroll
    for(int i=0;i<2;i++){
      int u = tid*2 + i;
      int kt = u >> 3, dc = u & 7;
      uint4 w = *(const uint4*)(kbase + (size_t)(t*64+kt)*2304 + dc*8);
      *(uint4*)((char*)Kt + kt*128 + ((dc*16) ^ ((kt&7)<<4))) = w;
      union { uint4 u4; u16 s[8]; } vv;
      vv.u4 = *(const uint4*)(vbase + (size_t)(t*64+kt)*2304 + dc*8);
      #pragma unroll
      for(int e=0;e<8;e++){
        int d = dc*8 + e;
        *(u16*)((char*)Vt + d*128 + ((kt*2) ^ ((d&7)<<4))) = vv.s[e];
      }
    }
    __syncthreads();
    f32x4 sacc[4];
    #pragma unroll
    for(int j=0;j<4;j++)
      #pragma unroll
      for(int r=0;r<4;r++) sacc[j][r]=0.f;
    #pragma unroll
    for(int ks=0; ks<2; ks++){
      bfv8 kb[4];
      #pragma unroll
      for(int j=0;j<4;j++){
        int kr = j*16 + cl;
        kb[j] = *(const bfv8*)((const char*)Kt + kr*128 + ((ks*64 + g*16) ^ ((kr&7)<<4)));
      }
      bfv8 qa = ks ? qf1 : qf0;
      #pragma unroll
      for(int j=0;j<4;j++)
        sacc[j] = __builtin_amdgcn_mfma_f32_16x16x32_bf16(qa, kb[j], sacc[j], 0, 0, 0);
    }
    if(t == qtile){
      #pragma unroll
      for(int j=0;j<4;j++)
        #pragma unroll
        for(int r=0;r<4;r++)
          if(cl + 16*j > wid*16 + g*4 + r) sacc[j][r] = -INFINITY;
    }
    // P -> per-wave LDS (A-frag layout), normalized
    #pragma unroll
    for(int j=0;j<4;j++){
      #pragma unroll
      for(int r=0;r<4;r++){
        float p = exp2f(SCL*(sacc[j][r]-m[r])) * inv[r];
        int row = g*4+r, col = cl+16*j;
        *(u16*)((char*)pr + row*128 + ((col*2) ^ ((row&7)<<4))) = f2bu(p);
      }
    }
    // PV accumulate (same-wave LDS dependency; compiler inserts lgkmcnt)
    #pragma unroll
    for(int ks=0; ks<2; ks++){
      bfv8 pa = *(const bfv8*)((const char*)pr + cl*128 + ((ks*64 + g*16) ^ ((cl&7)<<4)));
      bfv8 vb[4];
      #pragma unroll
      for(int j=0;j<4;j++){
        int d = j*16 + cl;
        vb[j] = *(const bfv8*)((const char*)Vt + d*128 + ((ks*64 + g*16) ^ ((d&7)<<4)));
      }
      #pragma unroll
      for(int j=0;j<4;j++)
        oacc[j] = __builtin_amdgcn_mfma_f32_16x16x32_bf16(pa, vb[j], oacc[j], 0, 0, 0);
    }
    // att map write from Ps (wave-private region)
    {
      int row = lane >> 2;
      size_t abase = attOff + (((size_t)bh*Tt) + qtile*64 + wid*16 + row)*Tt + t*64;
      #pragma unroll
      for(int i=0;i<2;i++){
        int bcol = (lane&3)*32 + 16*i;
        uint4 w = *(const uint4*)((const char*)pr + row*128 + (bcol ^ ((row&7)<<4)));
        int col = bcol >> 1;
        if(f32){
          union { uint4 u4; u16 s[8]; } pp; pp.u4 = w;
          float4 f0 = make_float4(bu2f(pp.s[0]),bu2f(pp.s[1]),bu2f(pp.s[2]),bu2f(pp.s[3]));
          float4 f1 = make_float4(bu2f(pp.s[4]),bu2f(pp.s[5]),bu2f(pp.s[6]),bu2f(pp.s[7]));
          *(float4*)((float*)attB + abase + col)     = f0;
          *(float4*)((float*)attB + abase + col + 4) = f1;
        } else {
          *(uint4*)((u16*)attB + abase + col) = w;
        }
      }
    }
  }

  // zero upper-triangle att tiles (t > qtile)
  {
    int row = lane >> 2;
    for(int t=qtile+1; t<8; ++t){
      size_t abase = attOff + (((size_t)bh*Tt) + qtile*64 + wid*16 + row)*Tt + t*64;
      #pragma unroll
      for(int i=0;i<2;i++){
        int col = (lane&3)*16 + i*8;
        if(f32){
          float4 z = make_float4(0.f,0.f,0.f,0.f);
          *(float4*)((float*)attB + abase + col)     = z;
          *(float4*)((float*)attB + abase + col + 4) = z;
        } else {
          uint4 z = {0,0,0,0};
          *(uint4*)((u16*)attB + abase + col) = z;
        }
      }
    }
  }

  // y write: O C/D layout row=g*4+r (q), col=cl+16j (d)
  #pragma unroll
  for(int j=0;j<4;j++){
    #pragma unroll
    for(int r=0;r<4;r++){
      int qr = qtile*64 + wid*16 + g*4 + r;
      y[((size_t)(b*Tt)+qr)*Cc + h*64 + cl + 16*j] = f2bu(oacc[j][r]);
    }
  }
}

extern "C" void kernel_launch(void* const* d_in, const int* in_sizes, int n_in,
                              void* d_out, int out_size, void* d_ws, size_t ws_size,
                              hipStream_t stream) {
  (void)in_sizes; (void)n_in; (void)out_size; (void)ws_size;
  const int*  idx  = (const int*)d_in[0];
  const void* tok  = d_in[1];
  const void* typ  = d_in[2];
  const void* pos  = d_in[3];
  const void* Wq   = d_in[4];
  const void* bq   = d_in[5];
  const void* Wk   = d_in[6];
  const void* bk   = d_in[7];
  const void* Wv   = d_in[8];
  const void* bv   = d_in[9];
  const void* Wp   = d_in[10];
  const void* bp   = d_in[11];
  const void* ln1w = d_in[12];
  const void* ln1b = d_in[13];
  const void* ln2w = d_in[14];
  const void* ln2b = d_in[15];
  const void* W1   = d_in[16];
  const void* b1   = d_in[17];
  const void* W2   = d_in[18];
  const void* b2   = d_in[19];
  const void* lnfw = d_in[20];
  const void* lnfb = d_in[21];
  const void* headw= d_in[22];

  const size_t NTC = (size_t)Bb*Tt*Cc;        // 1,572,864
  const size_t ATT_L = (size_t)Bb*Hh*Tt*Tt;   // 12,582,912
  const int M = Bb*Tt;                        // 2048

  float* x   = (float*)d_ws;
  u16* qkv   = (u16*)(x + NTC);               // [M][2304]
  u16* h     = qkv + (size_t)M*2304;
  u16* y     = h + NTC;
  u16* ff    = y + NTC;                       // [M][FF]
  u16* wqkvT = ff + (size_t)M*FFf;            // [2304][768]
  u16* wpT   = wqkvT + (size_t)2304*Cc;
  u16* w1T   = wpT + (size_t)Cc*Cc;           // [3072][768]
  u16* w2T   = w1T + (size_t)Cc*FFf;          // [768][3072]
  u16* hw    = w2T + (size_t)FFf*Cc;
  void* bqkv = (void*)(hw + (size_t)Vv*Cc);   // [L][2304] flag dtype
  int* flag  = (int*)((float*)bqkv + (size_t)Ll*2304);

  const size_t offX   = (size_t)Bb*Tt*Vv;
  const size_t offAtt = offX + NTC;

  dim3 blk(256);

  detect_kernel<<<1, blk, 0, stream>>>(tok, flag);
  embed_kernel<<<(Bb*Tt*Cc)/256, blk, 0, stream>>>(idx, tok, typ, pos, x, flag);
  conv_kernel<<<((Vv*Cc)/4)/256, blk, 0, stream>>>(headw, hw, flag);
  packb_kernel<<<(Ll*2304)/256, blk, 0, stream>>>(bq, bk, bv, bqkv, flag);

  for(int l=0; l<Ll; l++){
    const size_t vC = (size_t)l*Cc;
    const size_t vF = (size_t)l*FFf;
    const size_t attOff = offAtt + (size_t)l*ATT_L;

    transpose_all<<<6912, blk, 0, stream>>>(Wq, Wk, Wv, Wp, W1, W2, l,
                                            wqkvT, wpT, w1T, w2T, flag);

    ln_kernel<<<M, blk, 0, stream>>>(x, ln1w, ln1b, vC, h, nullptr, 0, flag);
    gemm_mfma<1,4,4,2,false,true><<<dim3(2304/128, M/64), blk, 0, stream>>>(
        h, wqkvT, bqkv, (size_t)l*2304, nullptr, qkv, nullptr, 0, 2304, Cc, flag);

    fattn_kernel<<<Bb*Hh*8, blk, 0, stream>>>(qkv, d_out, attOff, y, flag);

    gemm_mfma<2,2,2,2,false,false><<<dim3(Cc/64, M/64), blk, 0, stream>>>(
        y, wpT, bp, vC, x, x, nullptr, 0, Cc, Cc, flag);

    ln_kernel<<<M, blk, 0, stream>>>(x, ln2w, ln2b, vC, h, nullptr, 0, flag);
    gemm_mfma<2,2,4,4,true,true><<<dim3(FFf/128, M/128), blk, 0, stream>>>(
        h, w1T, b1, vF, nullptr, ff, nullptr, 0, FFf, Cc, flag);
    gemm_mfma<2,2,2,2,false,false><<<dim3(Cc/64, M/64), blk, 0, stream>>>(
        ff, w2T, b2, vC, x, x, nullptr, 0, Cc, FFf, flag);
  }

  ln_kernel<<<M, blk, 0, stream>>>(x, lnfw, lnfb, 0, h, d_out, offX, flag);
  gemm_mfma<2,2,2,2,false,false><<<dim3(Vv/64, M/64), blk, 0, stream>>>(
      h, hw, nullptr, 0, nullptr, nullptr, d_out, 0, Vv, Cc, flag);
}